// Round 2
// baseline (118.366 us; speedup 1.0000x reference)
//
#include <hip/hip_runtime.h>

// KGNN head: out[b,g,d] = sum_n ( dot(drug[b,g,:], rel[b,g,n,:]) * ent[b,g,n,d] )
// B=2048, n_shape=64, D=64, N_NEIGHBOR=8  -> 131072 independent groups.
// One 64-lane wave per GPW=8 groups, software-pipelined prefetch (load g+1
// while computing g) to keep ~10 float4 loads in flight per wave.

constexpr int BATCH   = 2048;
constexpr int NSHAPE  = 64;
constexpr int DIM     = 64;
constexpr int NGROUPS = BATCH * NSHAPE;          // 131072
constexpr int GPW     = 8;                       // groups per wave
constexpr int WAVES_PER_BLOCK = 4;               // 256 threads

__global__ __launch_bounds__(256) void kgnn_head_kernel(
    const float* __restrict__ drug,   // [B, 64, 64]
    const float* __restrict__ rel,    // [B, 512, 64]
    const float* __restrict__ ent,    // [B, 512, 64]
    float*       __restrict__ out)    // [B, 64, 64]
{
    const int wave_id = (int)((blockIdx.x * blockDim.x + threadIdx.x) >> 6);
    const int lane    = threadIdx.x & 63;
    const int pos     = lane & 15;               // float4 position within 64-float row

    const int g0 = wave_id * GPW;                // first group for this wave

    const float4* drug4 = reinterpret_cast<const float4*>(drug);
    const float4* rel4  = reinterpret_cast<const float4*>(rel);
    const float4* ent4  = reinterpret_cast<const float4*>(ent);
    float4*       out4  = reinterpret_cast<float4*>(out);

    // ---- prologue: load group g0 ----
    // drug: 16 float4 per group; rel/ent: 128 float4 per group (8 neighbors x 16)
    float4 dg = drug4[(size_t)g0 * 16 + pos];
    float4 r0 = rel4[(size_t)g0 * 128 + lane];
    float4 r1 = rel4[(size_t)g0 * 128 + 64 + lane];
    float4 e0 = ent4[(size_t)g0 * 128 + lane];
    float4 e1 = ent4[(size_t)g0 * 128 + 64 + lane];

    #pragma unroll
    for (int k = 0; k < GPW; ++k) {
        // capture current group's data
        const float4 dgc = dg, r0c = r0, r1c = r1, e0c = e0, e1c = e1;

        // ---- prefetch next group ----
        if (k + 1 < GPW) {
            const size_t g = (size_t)(g0 + k + 1);
            dg = drug4[g * 16 + pos];
            r0 = rel4[g * 128 + lane];
            r1 = rel4[g * 128 + 64 + lane];
            e0 = ent4[g * 128 + lane];
            e1 = ent4[g * 128 + 64 + lane];
        }

        // ---- compute group g0+k ----
        // partial dots over this lane's 4 dims (neighbor = pass*4 + (lane>>4))
        float p0 = dgc.x * r0c.x + dgc.y * r0c.y + dgc.z * r0c.z + dgc.w * r0c.w;
        float p1 = dgc.x * r1c.x + dgc.y * r1c.y + dgc.z * r1c.z + dgc.w * r1c.w;

        // reduce within 16-lane segment -> neighbor scores (2-wide ILP)
        p0 += __shfl_xor(p0, 1);  p1 += __shfl_xor(p1, 1);
        p0 += __shfl_xor(p0, 2);  p1 += __shfl_xor(p1, 2);
        p0 += __shfl_xor(p0, 4);  p1 += __shfl_xor(p1, 4);
        p0 += __shfl_xor(p0, 8);  p1 += __shfl_xor(p1, 8);

        float4 acc;
        acc.x = fmaf(p0, e0c.x, p1 * e1c.x);
        acc.y = fmaf(p0, e0c.y, p1 * e1c.y);
        acc.z = fmaf(p0, e0c.z, p1 * e1c.z);
        acc.w = fmaf(p0, e0c.w, p1 * e1c.w);

        // sum the 4 neighbor-segments: lanes l, l^16, l^32, l^48
        acc.x += __shfl_xor(acc.x, 16);
        acc.y += __shfl_xor(acc.y, 16);
        acc.z += __shfl_xor(acc.z, 16);
        acc.w += __shfl_xor(acc.w, 16);
        acc.x += __shfl_xor(acc.x, 32);
        acc.y += __shfl_xor(acc.y, 32);
        acc.z += __shfl_xor(acc.z, 32);
        acc.w += __shfl_xor(acc.w, 32);

        if (lane < 16) {
            out4[(size_t)(g0 + k) * 16 + pos] = acc;
        }
    }
}

extern "C" void kernel_launch(void* const* d_in, const int* in_sizes, int n_in,
                              void* d_out, int out_size, void* d_ws, size_t ws_size,
                              hipStream_t stream) {
    const float* drug = (const float*)d_in[0];
    const float* rel  = (const float*)d_in[1];
    const float* ent  = (const float*)d_in[2];
    float* out = (float*)d_out;

    const int blocks = NGROUPS / (GPW * WAVES_PER_BLOCK);  // 4096
    kgnn_head_kernel<<<blocks, WAVES_PER_BLOCK * 64, 0, stream>>>(drug, rel, ent, out);
}

// Round 3
// 106.878 us; speedup vs baseline: 1.1075x; 1.1075x over previous
//
#include <hip/hip_runtime.h>

// KGNN head: out[b,g,d] = sum_n ( dot(drug[b,g,:], rel[b,g,n,:]) * ent[b,g,n,d] )
// B=2048, n_shape=64, D=64, N_NEIGHBOR=8 -> 131072 independent groups.
// R3: 2 groups per wave, ALL 10 float4 loads issued up-front (10-deep MLP),
// 2-wide ILP through the shuffle reductions, combined 32-lane contiguous
// non-temporal store (two adjacent groups -> 512B).

constexpr int BATCH   = 2048;
constexpr int NSHAPE  = 64;
constexpr int NGROUPS = BATCH * NSHAPE;          // 131072
constexpr int WAVES_PER_BLOCK = 4;               // 256 threads

typedef float f32x4 __attribute__((ext_vector_type(4)));

__global__ __launch_bounds__(256) void kgnn_head_kernel(
    const float* __restrict__ drug,   // [B, 64, 64]
    const float* __restrict__ rel,    // [B, 512, 64]
    const float* __restrict__ ent,    // [B, 512, 64]
    float*       __restrict__ out)    // [B, 64, 64]
{
    const int wave_id = (int)((blockIdx.x * blockDim.x + threadIdx.x) >> 6);
    const int lane    = threadIdx.x & 63;
    const int pos     = lane & 15;               // float4 position within 64-float row

    const int gA = wave_id * 2;                  // two adjacent groups per wave

    const f32x4* drug4 = reinterpret_cast<const f32x4*>(drug);
    const f32x4* rel4  = reinterpret_cast<const f32x4*>(rel);
    const f32x4* ent4  = reinterpret_cast<const f32x4*>(ent);
    f32x4*       out4  = reinterpret_cast<f32x4*>(out);

    const size_t dbase = (size_t)gA * 16;        // drug/out float4 base
    const size_t rbase = (size_t)gA * 128;       // rel/ent float4 base (2 groups = 256)

    // ---- issue all 10 loads back-to-back (10-deep MLP) ----
    const f32x4 dgA = drug4[dbase + pos];
    const f32x4 dgB = drug4[dbase + 16 + pos];
    const f32x4 rA0 = rel4[rbase + lane];
    const f32x4 rA1 = rel4[rbase + 64 + lane];
    const f32x4 rB0 = rel4[rbase + 128 + lane];
    const f32x4 rB1 = rel4[rbase + 192 + lane];
    const f32x4 eA0 = ent4[rbase + lane];
    const f32x4 eA1 = ent4[rbase + 64 + lane];
    const f32x4 eB0 = ent4[rbase + 128 + lane];
    const f32x4 eB1 = ent4[rbase + 192 + lane];

    // ---- partial dots (lane's 4 dims; neighbor = pass*4 + (lane>>4)) ----
    float pA0 = dgA.x * rA0.x + dgA.y * rA0.y + dgA.z * rA0.z + dgA.w * rA0.w;
    float pA1 = dgA.x * rA1.x + dgA.y * rA1.y + dgA.z * rA1.z + dgA.w * rA1.w;
    float pB0 = dgB.x * rB0.x + dgB.y * rB0.y + dgB.z * rB0.z + dgB.w * rB0.w;
    float pB1 = dgB.x * rB1.x + dgB.y * rB1.y + dgB.z * rB1.z + dgB.w * rB1.w;

    // ---- 16-lane segment reduction -> neighbor scores (4-wide ILP) ----
    pA0 += __shfl_xor(pA0, 1);  pA1 += __shfl_xor(pA1, 1);
    pB0 += __shfl_xor(pB0, 1);  pB1 += __shfl_xor(pB1, 1);
    pA0 += __shfl_xor(pA0, 2);  pA1 += __shfl_xor(pA1, 2);
    pB0 += __shfl_xor(pB0, 2);  pB1 += __shfl_xor(pB1, 2);
    pA0 += __shfl_xor(pA0, 4);  pA1 += __shfl_xor(pA1, 4);
    pB0 += __shfl_xor(pB0, 4);  pB1 += __shfl_xor(pB1, 4);
    pA0 += __shfl_xor(pA0, 8);  pA1 += __shfl_xor(pA1, 8);
    pB0 += __shfl_xor(pB0, 8);  pB1 += __shfl_xor(pB1, 8);

    // ---- weighted accumulate ----
    f32x4 accA, accB;
    accA.x = fmaf(pA0, eA0.x, pA1 * eA1.x);
    accA.y = fmaf(pA0, eA0.y, pA1 * eA1.y);
    accA.z = fmaf(pA0, eA0.z, pA1 * eA1.z);
    accA.w = fmaf(pA0, eA0.w, pA1 * eA1.w);
    accB.x = fmaf(pB0, eB0.x, pB1 * eB1.x);
    accB.y = fmaf(pB0, eB0.y, pB1 * eB1.y);
    accB.z = fmaf(pB0, eB0.z, pB1 * eB1.z);
    accB.w = fmaf(pB0, eB0.w, pB1 * eB1.w);

    // ---- sum the 4 neighbor-segments (result replicated to all lanes) ----
    accA.x += __shfl_xor(accA.x, 16);  accB.x += __shfl_xor(accB.x, 16);
    accA.y += __shfl_xor(accA.y, 16);  accB.y += __shfl_xor(accB.y, 16);
    accA.z += __shfl_xor(accA.z, 16);  accB.z += __shfl_xor(accB.z, 16);
    accA.w += __shfl_xor(accA.w, 16);  accB.w += __shfl_xor(accB.w, 16);
    accA.x += __shfl_xor(accA.x, 32);  accB.x += __shfl_xor(accB.x, 32);
    accA.y += __shfl_xor(accA.y, 32);  accB.y += __shfl_xor(accB.y, 32);
    accA.z += __shfl_xor(accA.z, 32);  accB.z += __shfl_xor(accB.z, 32);
    accA.w += __shfl_xor(accA.w, 32);  accB.w += __shfl_xor(accB.w, 32);

    // ---- combined 32-lane contiguous store (512B across two adjacent groups) ----
    if (lane < 32) {
        const f32x4 v = (lane < 16) ? accA : accB;   // lane L holds pos L&15 after replication
        __builtin_nontemporal_store(v, &out4[dbase + lane]);
    }
}

extern "C" void kernel_launch(void* const* d_in, const int* in_sizes, int n_in,
                              void* d_out, int out_size, void* d_ws, size_t ws_size,
                              hipStream_t stream) {
    const float* drug = (const float*)d_in[0];
    const float* rel  = (const float*)d_in[1];
    const float* ent  = (const float*)d_in[2];
    float* out = (float*)d_out;

    const int blocks = NGROUPS / (2 * WAVES_PER_BLOCK);  // 16384
    kgnn_head_kernel<<<blocks, WAVES_PER_BLOCK * 64, 0, stream>>>(drug, rel, ent, out);
}

// Round 4
// 96.385 us; speedup vs baseline: 1.2281x; 1.1089x over previous
//
#include <hip/hip_runtime.h>

// KGNN head: out[b,g,d] = sum_n ( dot(drug[b,g,:], rel[b,g,n,:]) * ent[b,g,n,d] )
// B=2048, n_shape=64, D=64, N_NEIGHBOR=8 -> 131072 independent groups.
// R4: R3 structure (2 groups/wave, 10 float4 loads up-front, combined 32-lane
// contiguous store) + NON-TEMPORAL loads: the 570MB input is a read-once
// stream (>> L2+IC capacity), so bypassing cache retention recovers
// fill/evict overhead in TCC.

constexpr int BATCH   = 2048;
constexpr int NSHAPE  = 64;
constexpr int NGROUPS = BATCH * NSHAPE;          // 131072
constexpr int WAVES_PER_BLOCK = 4;               // 256 threads

typedef float f32x4 __attribute__((ext_vector_type(4)));

__device__ __forceinline__ f32x4 ntload(const f32x4* p) {
    return __builtin_nontemporal_load(p);
}

__global__ __launch_bounds__(256) void kgnn_head_kernel(
    const float* __restrict__ drug,   // [B, 64, 64]
    const float* __restrict__ rel,    // [B, 512, 64]
    const float* __restrict__ ent,    // [B, 512, 64]
    float*       __restrict__ out)    // [B, 64, 64]
{
    const int wave_id = (int)((blockIdx.x * blockDim.x + threadIdx.x) >> 6);
    const int lane    = threadIdx.x & 63;
    const int pos     = lane & 15;               // float4 position within 64-float row

    const int gA = wave_id * 2;                  // two adjacent groups per wave

    const f32x4* drug4 = reinterpret_cast<const f32x4*>(drug);
    const f32x4* rel4  = reinterpret_cast<const f32x4*>(rel);
    const f32x4* ent4  = reinterpret_cast<const f32x4*>(ent);
    f32x4*       out4  = reinterpret_cast<f32x4*>(out);

    const size_t dbase = (size_t)gA * 16;        // drug/out float4 base
    const size_t rbase = (size_t)gA * 128;       // rel/ent float4 base (2 groups = 256)

    // ---- issue all 10 loads back-to-back (10-deep MLP), non-temporal ----
    const f32x4 dgA = ntload(&drug4[dbase + pos]);
    const f32x4 dgB = ntload(&drug4[dbase + 16 + pos]);
    const f32x4 rA0 = ntload(&rel4[rbase + lane]);
    const f32x4 rA1 = ntload(&rel4[rbase + 64 + lane]);
    const f32x4 rB0 = ntload(&rel4[rbase + 128 + lane]);
    const f32x4 rB1 = ntload(&rel4[rbase + 192 + lane]);
    const f32x4 eA0 = ntload(&ent4[rbase + lane]);
    const f32x4 eA1 = ntload(&ent4[rbase + 64 + lane]);
    const f32x4 eB0 = ntload(&ent4[rbase + 128 + lane]);
    const f32x4 eB1 = ntload(&ent4[rbase + 192 + lane]);

    // ---- partial dots (lane's 4 dims; neighbor = pass*4 + (lane>>4)) ----
    float pA0 = dgA.x * rA0.x + dgA.y * rA0.y + dgA.z * rA0.z + dgA.w * rA0.w;
    float pA1 = dgA.x * rA1.x + dgA.y * rA1.y + dgA.z * rA1.z + dgA.w * rA1.w;
    float pB0 = dgB.x * rB0.x + dgB.y * rB0.y + dgB.z * rB0.z + dgB.w * rB0.w;
    float pB1 = dgB.x * rB1.x + dgB.y * rB1.y + dgB.z * rB1.z + dgB.w * rB1.w;

    // ---- 16-lane segment reduction -> neighbor scores (4-wide ILP) ----
    pA0 += __shfl_xor(pA0, 1);  pA1 += __shfl_xor(pA1, 1);
    pB0 += __shfl_xor(pB0, 1);  pB1 += __shfl_xor(pB1, 1);
    pA0 += __shfl_xor(pA0, 2);  pA1 += __shfl_xor(pA1, 2);
    pB0 += __shfl_xor(pB0, 2);  pB1 += __shfl_xor(pB1, 2);
    pA0 += __shfl_xor(pA0, 4);  pA1 += __shfl_xor(pA1, 4);
    pB0 += __shfl_xor(pB0, 4);  pB1 += __shfl_xor(pB1, 4);
    pA0 += __shfl_xor(pA0, 8);  pA1 += __shfl_xor(pA1, 8);
    pB0 += __shfl_xor(pB0, 8);  pB1 += __shfl_xor(pB1, 8);

    // ---- weighted accumulate ----
    f32x4 accA, accB;
    accA.x = fmaf(pA0, eA0.x, pA1 * eA1.x);
    accA.y = fmaf(pA0, eA0.y, pA1 * eA1.y);
    accA.z = fmaf(pA0, eA0.z, pA1 * eA1.z);
    accA.w = fmaf(pA0, eA0.w, pA1 * eA1.w);
    accB.x = fmaf(pB0, eB0.x, pB1 * eB1.x);
    accB.y = fmaf(pB0, eB0.y, pB1 * eB1.y);
    accB.z = fmaf(pB0, eB0.z, pB1 * eB1.z);
    accB.w = fmaf(pB0, eB0.w, pB1 * eB1.w);

    // ---- sum the 4 neighbor-segments (result replicated to all lanes) ----
    accA.x += __shfl_xor(accA.x, 16);  accB.x += __shfl_xor(accB.x, 16);
    accA.y += __shfl_xor(accA.y, 16);  accB.y += __shfl_xor(accB.y, 16);
    accA.z += __shfl_xor(accA.z, 16);  accB.z += __shfl_xor(accB.z, 16);
    accA.w += __shfl_xor(accA.w, 16);  accB.w += __shfl_xor(accB.w, 16);
    accA.x += __shfl_xor(accA.x, 32);  accB.x += __shfl_xor(accB.x, 32);
    accA.y += __shfl_xor(accA.y, 32);  accB.y += __shfl_xor(accB.y, 32);
    accA.z += __shfl_xor(accA.z, 32);  accB.z += __shfl_xor(accB.z, 32);
    accA.w += __shfl_xor(accA.w, 32);  accB.w += __shfl_xor(accB.w, 32);

    // ---- combined 32-lane contiguous store (512B across two adjacent groups) ----
    if (lane < 32) {
        const f32x4 v = (lane < 16) ? accA : accB;   // lane L holds pos L&15 after replication
        __builtin_nontemporal_store(v, &out4[dbase + lane]);
    }
}

extern "C" void kernel_launch(void* const* d_in, const int* in_sizes, int n_in,
                              void* d_out, int out_size, void* d_ws, size_t ws_size,
                              hipStream_t stream) {
    const float* drug = (const float*)d_in[0];
    const float* rel  = (const float*)d_in[1];
    const float* ent  = (const float*)d_in[2];
    float* out = (float*)d_out;

    const int blocks = NGROUPS / (2 * WAVES_PER_BLOCK);  // 16384
    kgnn_head_kernel<<<blocks, WAVES_PER_BLOCK * 64, 0, stream>>>(drug, rel, ent, out);
}